// Round 1
// baseline (501.028 us; speedup 1.0000x reference)
//
#include <hip/hip_runtime.h>

#define NEWL 150
#define EMBD 64
#define NCOL 256
#define CIMU 48
#define CEMG 16

#define BM 64
#define BN 128
#define KB 16
#define KCH 1200

// ---------- K0: combined weights  W_comb[s*C+c][j] = sum_e wemb[c][e] * w_proj[s*64+e][j]
__global__ __launch_bounds__(256) void wcomb_kernel(
    const float* __restrict__ w_emb_imu, const float* __restrict__ w_emb_emg,
    const float* __restrict__ w_proj,
    float* __restrict__ wc_imu, float* __restrict__ wc_emg) {
  const int s = blockIdx.x;   // 0..149
  const int m = blockIdx.y;   // 0 = imu, 1 = emg
  const int j = threadIdx.x;  // 0..255
  const int C = (m == 0) ? CIMU : CEMG;
  const float* wemb = (m == 0) ? w_emb_imu : w_emb_emg;
  float* out = (m == 0) ? (wc_imu + (size_t)s * CIMU * NCOL)
                        : (wc_emg + (size_t)s * CEMG * NCOL);
  // register-cache the 64x256 w_proj slice column j
  float wreg[EMBD];
  const float* wp = w_proj + (size_t)s * EMBD * NCOL + j;
#pragma unroll
  for (int e = 0; e < EMBD; ++e) wreg[e] = wp[(size_t)e * NCOL];
  for (int c = 0; c < C; ++c) {
    const float* we = wemb + c * EMBD;  // uniform -> scalar loads
    float acc = 0.f;
#pragma unroll
    for (int e = 0; e < EMBD; ++e) acc = fmaf(we[e], wreg[e], acc);
    out[(size_t)c * NCOL + j] = acc;
  }
}

// ---------- K1: bias_m[j] = b_proj[j] + sum_{s,e} b_emb_m[e] * w_proj[s*64+e][j]
__global__ __launch_bounds__(256) void bias_partial_kernel(
    const float* __restrict__ b_emb_imu, const float* __restrict__ b_emb_emg,
    const float* __restrict__ w_proj, float* __restrict__ bpart) {
  const int s = blockIdx.x, m = blockIdx.y, j = threadIdx.x;
  const float* be = (m == 0) ? b_emb_imu : b_emb_emg;
  const float* wp = w_proj + (size_t)s * EMBD * NCOL + j;
  float acc = 0.f;
#pragma unroll
  for (int e = 0; e < EMBD; ++e) acc = fmaf(be[e], wp[(size_t)e * NCOL], acc);
  bpart[((size_t)m * NEWL + s) * NCOL + j] = acc;
}

__global__ __launch_bounds__(256) void bias_reduce_kernel(
    const float* __restrict__ b_proj, const float* __restrict__ bpart,
    float* __restrict__ bias) {
  const int m = blockIdx.x, j = threadIdx.x;
  float acc = b_proj[j];
  for (int s = 0; s < NEWL; ++s) acc += bpart[((size_t)m * NEWL + s) * NCOL + j];
  bias[m * NCOL + j] = acc;
}

// ---------- K2: ragged linear interp on RAW channels (one wave per (b,s))
__global__ __launch_bounds__(256) void interp_kernel(
    const float* __restrict__ x_imu, const float* __restrict__ x_emg,
    const int* __restrict__ lens,
    float* __restrict__ xi_imu, float* __restrict__ xi_emg, int B, int T) {
  const int gid = blockIdx.x * 4 + (threadIdx.x >> 6);  // (b,s) pair index
  const int lane = threadIdx.x & 63;
  const int b = gid / NEWL;
  const int s = gid - b * NEWL;
  if (b >= B) return;
  const int len = lens[b];
  const float scale = (float)len / 150.0f;
  float src = ((float)s + 0.5f) * scale - 0.5f;
  src = fmaxf(src, 0.0f);
  int i0 = (int)floorf(src);
  i0 = min(i0, len - 1);
  const int i1 = min(i0 + 1, len - 1);
  const float w = src - (float)i0;
  if (lane < CIMU) {
    const int c = lane;
    const float* p = x_imu + (size_t)b * T * CIMU;
    const float v0 = p[(size_t)i0 * CIMU + c];
    const float v1 = p[(size_t)i1 * CIMU + c];
    xi_imu[((size_t)b * NEWL + s) * CIMU + c] = v0 * (1.0f - w) + v1 * w;
  } else {
    const int c = lane - CIMU;
    const float* p = x_emg + (size_t)b * T * CEMG;
    const float v0 = p[(size_t)i0 * CEMG + c];
    const float v1 = p[(size_t)i1 * CEMG + c];
    xi_emg[((size_t)b * NEWL + s) * CEMG + c] = v0 * (1.0f - w) + v1 * w;
  }
}

// ---------- K3: f32 GEMM, all 512 blocks do identical K=1200 work
// imu: M=B K=7200 (6 chunks), emg: M=B K=2400 (2 chunks); N=256 split in 2
__global__ __launch_bounds__(256) void gemm_kernel(
    const float* __restrict__ xi_imu, const float* __restrict__ xi_emg,
    const float* __restrict__ wc_imu, const float* __restrict__ wc_emg,
    float* __restrict__ p_imu, float* __restrict__ p_emg, int B) {
  __shared__ float a_lds[KB][BM];
  const int mtiles = B / BM;      // 32
  const int upk = mtiles * 2;     // 64 units per k-chunk
  const int unit = blockIdx.x;
  const float* A;
  const float* W;
  float* P;
  int Ktot, kofs, mb, nb;
  if (unit < 6 * upk) {
    const int kc = unit / upk, t = unit % upk;
    A = xi_imu; W = wc_imu; Ktot = NEWL * CIMU; kofs = kc * KCH;
    P = p_imu + (size_t)kc * B * NCOL;
    mb = t >> 1; nb = t & 1;
  } else {
    const int u = unit - 6 * upk;
    const int kc = u / upk, t = u % upk;
    A = xi_emg; W = wc_emg; Ktot = NEWL * CEMG; kofs = kc * KCH;
    P = p_emg + (size_t)kc * B * NCOL;
    mb = t >> 1; nb = t & 1;
  }
  const int tid = threadIdx.x;
  const int ct = tid & 31;   // col group (4 cols)
  const int rt = tid >> 5;   // row group (8 rows)
  const int col = nb * BN + ct * 4;
  const int row0 = mb * BM;
  const int sr = tid & 63;         // staging row
  const int sk = (tid >> 6) * 4;   // staging k offset
  const float* astage = A + (size_t)(row0 + sr) * Ktot + kofs + sk;

  float acc[8][4];
#pragma unroll
  for (int i = 0; i < 8; ++i)
#pragma unroll
    for (int jj = 0; jj < 4; ++jj) acc[i][jj] = 0.f;

  for (int kb = 0; kb < KCH; kb += KB) {
    const float4 av = *(const float4*)(astage + kb);  // prefetch before barrier
    __syncthreads();  // previous chunk fully consumed
    a_lds[sk + 0][sr] = av.x;
    a_lds[sk + 1][sr] = av.y;
    a_lds[sk + 2][sr] = av.z;
    a_lds[sk + 3][sr] = av.w;
    __syncthreads();
    const float* wp = W + (size_t)(kofs + kb) * NCOL + col;
#pragma unroll
    for (int k = 0; k < KB; ++k) {
      const float4 bv = *(const float4*)(wp + (size_t)k * NCOL);
      const float4 a0 = *(const float4*)(&a_lds[k][rt * 8]);
      const float4 a1 = *(const float4*)(&a_lds[k][rt * 8 + 4]);
      const float ar[8] = {a0.x, a0.y, a0.z, a0.w, a1.x, a1.y, a1.z, a1.w};
      const float br[4] = {bv.x, bv.y, bv.z, bv.w};
#pragma unroll
      for (int i = 0; i < 8; ++i)
#pragma unroll
        for (int jj = 0; jj < 4; ++jj)
          acc[i][jj] = fmaf(ar[i], br[jj], acc[i][jj]);
    }
  }
#pragma unroll
  for (int i = 0; i < 8; ++i) {
    float4 v;
    v.x = acc[i][0]; v.y = acc[i][1]; v.z = acc[i][2]; v.w = acc[i][3];
    *(float4*)(P + (size_t)(row0 + rt * 8 + i) * NCOL + col) = v;
  }
}

// ---------- K4: sum K-chunk partials + bias -> d_out
__global__ __launch_bounds__(256) void combine_kernel(
    const float* __restrict__ bias, const float* __restrict__ p_imu,
    const float* __restrict__ p_emg, float* __restrict__ out, int B) {
  const int b = blockIdx.x, m = blockIdx.y, j = threadIdx.x;
  const size_t n = (size_t)B * NCOL;
  const size_t o = (size_t)b * NCOL + j;
  if (m == 0) {
    float v = bias[j];
#pragma unroll
    for (int c = 0; c < 6; ++c) v += p_imu[c * n + o];
    out[o] = v;
  } else {
    out[n + o] = bias[NCOL + j] + p_emg[o] + p_emg[n + o];
  }
}

extern "C" void kernel_launch(void* const* d_in, const int* in_sizes, int n_in,
                              void* d_out, int out_size, void* d_ws, size_t ws_size,
                              hipStream_t stream) {
  const float* x_imu     = (const float*)d_in[0];
  const float* x_emg     = (const float*)d_in[1];
  const int*   lens      = (const int*)d_in[2];
  const float* w_emb_imu = (const float*)d_in[3];
  const float* b_emb_imu = (const float*)d_in[4];
  const float* w_emb_emg = (const float*)d_in[5];
  const float* b_emb_emg = (const float*)d_in[6];
  const float* w_proj    = (const float*)d_in[7];
  const float* b_proj    = (const float*)d_in[8];
  float* out = (float*)d_out;

  const int B = in_sizes[2];
  const int T = in_sizes[0] / (B * CIMU);

  // workspace layout (floats)
  float* ws = (float*)d_ws;
  float* wc_imu = ws;                               // 150*48*256
  float* wc_emg = wc_imu + (size_t)NEWL * CIMU * NCOL;  // 150*16*256
  float* bias   = wc_emg + (size_t)NEWL * CEMG * NCOL;  // 2*256
  float* bpart  = bias + 2 * NCOL;                  // 2*150*256
  float* xi_imu = bpart + (size_t)2 * NEWL * NCOL;  // B*7200
  float* xi_emg = xi_imu + (size_t)B * NEWL * CIMU; // B*2400
  float* p_imu  = xi_emg + (size_t)B * NEWL * CEMG; // 6*B*256
  float* p_emg  = p_imu + (size_t)6 * B * NCOL;     // 2*B*256

  wcomb_kernel<<<dim3(NEWL, 2), 256, 0, stream>>>(w_emb_imu, w_emb_emg, w_proj,
                                                  wc_imu, wc_emg);
  bias_partial_kernel<<<dim3(NEWL, 2), 256, 0, stream>>>(b_emb_imu, b_emb_emg,
                                                         w_proj, bpart);
  bias_reduce_kernel<<<2, 256, 0, stream>>>(b_proj, bpart, bias);
  interp_kernel<<<(B * NEWL + 3) / 4, 256, 0, stream>>>(x_imu, x_emg, lens,
                                                        xi_imu, xi_emg, B, T);
  const int upk = (B / BM) * 2;  // 64
  gemm_kernel<<<8 * upk, 256, 0, stream>>>(xi_imu, xi_emg, wc_imu, wc_emg,
                                           p_imu, p_emg, B);
  combine_kernel<<<dim3(B, 2), 256, 0, stream>>>(bias, p_imu, p_emg, out, B);
}

// Round 2
// 177.806 us; speedup vs baseline: 2.8178x; 2.8178x over previous
//
#include <hip/hip_runtime.h>

#define NEWL 150
#define EMBD 64
#define NCOL 256
#define CIMU 48
#define CEMG 16

#define KIMU (NEWL * CIMU)  // 7200
#define KEMG (NEWL * CEMG)  // 2400
#define KCH 800             // k-chunk (25 mfma steps of 32)
#define KSTEPS (KCH / 32)   // 25
#define NCI (KIMU / KCH)    // 9 imu chunks
#define NCE (KEMG / KCH)    // 3 emg chunks

typedef __bf16 bf16x8_t __attribute__((ext_vector_type(8)));
typedef float f32x4_t __attribute__((ext_vector_type(4)));

__device__ inline f32x4_t mfma16(bf16x8_t a, bf16x8_t b, f32x4_t c) {
  return __builtin_amdgcn_mfma_f32_16x16x32_bf16(a, b, c, 0, 0, 0);
}

// ---------- K0: combined weights, TRANSPOSED + bf16:
// wcT[j][k= s*C+c] = sum_e wemb[c][e] * w_proj[s*64+e][j]
template <int C>
__device__ void wcomb_body(const float* __restrict__ wemb,
                           const float* __restrict__ wp_base,
                           __bf16* __restrict__ out) {
  float wreg[EMBD];
#pragma unroll
  for (int e = 0; e < EMBD; ++e) wreg[e] = wp_base[(size_t)e * NCOL];
#pragma unroll
  for (int v = 0; v < C / 8; ++v) {
    bf16x8_t t;
#pragma unroll
    for (int q = 0; q < 8; ++q) {
      const float* we = wemb + (v * 8 + q) * EMBD;
      float acc = 0.f;
#pragma unroll
      for (int e = 0; e < EMBD; ++e) acc = fmaf(we[e], wreg[e], acc);
      t[q] = (__bf16)acc;
    }
    *(bf16x8_t*)(out + v * 8) = t;
  }
}

__global__ __launch_bounds__(256) void wcomb_kernel(
    const float* __restrict__ w_emb_imu, const float* __restrict__ w_emb_emg,
    const float* __restrict__ w_proj,
    __bf16* __restrict__ wcT_imu, __bf16* __restrict__ wcT_emg) {
  const int s = blockIdx.x;   // 0..149
  const int m = blockIdx.y;   // 0 = imu, 1 = emg
  const int j = threadIdx.x;  // output column 0..255
  const float* wp_base = w_proj + (size_t)s * EMBD * NCOL + j;
  if (m == 0)
    wcomb_body<CIMU>(w_emb_imu, wp_base, wcT_imu + (size_t)j * KIMU + s * CIMU);
  else
    wcomb_body<CEMG>(w_emb_emg, wp_base, wcT_emg + (size_t)j * KEMG + s * CEMG);
}

// ---------- K1: bias_m[j] = b_proj[j] + sum_{s,e} b_emb_m[e] * w_proj[s*64+e][j]
__global__ __launch_bounds__(256) void bias_partial_kernel(
    const float* __restrict__ b_emb_imu, const float* __restrict__ b_emb_emg,
    const float* __restrict__ w_proj, float* __restrict__ bpart) {
  const int s = blockIdx.x, m = blockIdx.y, j = threadIdx.x;
  const float* be = (m == 0) ? b_emb_imu : b_emb_emg;
  const float* wp = w_proj + (size_t)s * EMBD * NCOL + j;
  float acc = 0.f;
#pragma unroll
  for (int e = 0; e < EMBD; ++e) acc = fmaf(be[e], wp[(size_t)e * NCOL], acc);
  bpart[((size_t)m * NEWL + s) * NCOL + j] = acc;
}

__global__ __launch_bounds__(256) void bias_reduce_kernel(
    const float* __restrict__ b_proj, const float* __restrict__ bpart,
    float* __restrict__ bias) {
  const int m = blockIdx.x, j = threadIdx.x;
  float acc = b_proj[j];
  for (int s = 0; s < NEWL; ++s) acc += bpart[((size_t)m * NEWL + s) * NCOL + j];
  bias[m * NCOL + j] = acc;
}

// ---------- K2: ragged linear interp on RAW channels -> bf16 (one wave per (b,s))
__global__ __launch_bounds__(256) void interp_kernel(
    const float* __restrict__ x_imu, const float* __restrict__ x_emg,
    const int* __restrict__ lens,
    __bf16* __restrict__ xi_imu, __bf16* __restrict__ xi_emg, int B, int T) {
  const int gid = blockIdx.x * 4 + (threadIdx.x >> 6);  // (b,s) pair index
  const int lane = threadIdx.x & 63;
  const int b = gid / NEWL;
  const int s = gid - b * NEWL;
  if (b >= B) return;
  const int len = lens[b];
  const float scale = (float)len / 150.0f;
  float src = ((float)s + 0.5f) * scale - 0.5f;
  src = fmaxf(src, 0.0f);
  int i0 = (int)floorf(src);
  i0 = min(i0, len - 1);
  const int i1 = min(i0 + 1, len - 1);
  const float w = src - (float)i0;
  if (lane < CIMU) {
    const int c = lane;
    const float* p = x_imu + (size_t)b * T * CIMU;
    const float v0 = p[(size_t)i0 * CIMU + c];
    const float v1 = p[(size_t)i1 * CIMU + c];
    xi_imu[((size_t)b * NEWL + s) * CIMU + c] = (__bf16)(v0 * (1.0f - w) + v1 * w);
  } else {
    const int c = lane - CIMU;
    const float* p = x_emg + (size_t)b * T * CEMG;
    const float v0 = p[(size_t)i0 * CEMG + c];
    const float v1 = p[(size_t)i1 * CEMG + c];
    xi_emg[((size_t)b * NEWL + s) * CEMG + c] = (__bf16)(v0 * (1.0f - w) + v1 * w);
  }
}

// ---------- K3: bf16 MFMA GEMM, no LDS; K split into 800-chunks -> f32 partials
// block = 64x64 tile (4 waves, each 32x32 = 2x2 fragments of 16x16x32)
__global__ __launch_bounds__(256) void mfma_gemm_kernel(
    const __bf16* __restrict__ xi_imu, const __bf16* __restrict__ xi_emg,
    const __bf16* __restrict__ wT_imu, const __bf16* __restrict__ wT_emg,
    float* __restrict__ p_imu, float* __restrict__ p_emg, int B) {
  const int mtiles = B / 64;      // 32
  const int upk = mtiles * 4;     // 128 units per k-chunk (ntiles = 4)
  int unit = blockIdx.x;
  const __bf16 *A, *W;
  float* P;
  int Ktot, kofs, mb, nb;
  if (unit < NCI * upk) {
    const int kc = unit / upk, t = unit % upk;
    A = xi_imu; W = wT_imu; Ktot = KIMU; kofs = kc * KCH;
    P = p_imu + (size_t)kc * B * NCOL;
    mb = t >> 2; nb = t & 3;
  } else {
    unit -= NCI * upk;
    const int kc = unit / upk, t = unit % upk;
    A = xi_emg; W = wT_emg; Ktot = KEMG; kofs = kc * KCH;
    P = p_emg + (size_t)kc * B * NCOL;
    mb = t >> 2; nb = t & 3;
  }
  const int tid = threadIdx.x, w = tid >> 6, l = tid & 63;
  const int wr = w >> 1, wn = w & 1;
  const int lr = l & 15, lk = (l >> 4) * 8;
  const int row0 = mb * 64 + wr * 32;
  const int col0 = nb * 64 + wn * 32;
  const __bf16* a0 = A + (size_t)(row0 + lr) * Ktot + kofs + lk;
  const __bf16* a1 = a0 + (size_t)16 * Ktot;
  const __bf16* b0 = W + (size_t)(col0 + lr) * Ktot + kofs + lk;
  const __bf16* b1 = b0 + (size_t)16 * Ktot;

  f32x4_t acc00 = {0.f, 0.f, 0.f, 0.f}, acc01 = acc00, acc10 = acc00, acc11 = acc00;
#pragma unroll 5
  for (int ks = 0; ks < KSTEPS; ++ks) {
    const int o = ks * 32;
    const bf16x8_t av0 = *(const bf16x8_t*)(a0 + o);
    const bf16x8_t av1 = *(const bf16x8_t*)(a1 + o);
    const bf16x8_t bv0 = *(const bf16x8_t*)(b0 + o);
    const bf16x8_t bv1 = *(const bf16x8_t*)(b1 + o);
    acc00 = mfma16(av0, bv0, acc00);
    acc01 = mfma16(av0, bv1, acc01);
    acc10 = mfma16(av1, bv0, acc10);
    acc11 = mfma16(av1, bv1, acc11);
  }
  // C/D layout: col = lane&15, row = (lane>>4)*4 + reg
  const int orow = (l >> 4) * 4, ocol = l & 15;
  float* Pb = P + (size_t)(row0 + orow) * NCOL + col0 + ocol;
#pragma unroll
  for (int j = 0; j < 4; ++j) {
    Pb[(size_t)j * NCOL] = acc00[j];
    Pb[(size_t)j * NCOL + 16] = acc01[j];
    Pb[(size_t)(16 + j) * NCOL] = acc10[j];
    Pb[(size_t)(16 + j) * NCOL + 16] = acc11[j];
  }
}

// ---------- K4: sum K-chunk partials + bias -> d_out
__global__ __launch_bounds__(256) void combine_kernel(
    const float* __restrict__ bias, const float* __restrict__ p_imu,
    const float* __restrict__ p_emg, float* __restrict__ out, int B) {
  const int b = blockIdx.x, m = blockIdx.y, j = threadIdx.x;
  const size_t n = (size_t)B * NCOL;
  const size_t o = (size_t)b * NCOL + j;
  if (m == 0) {
    float v = bias[j];
#pragma unroll
    for (int c = 0; c < NCI; ++c) v += p_imu[c * n + o];
    out[o] = v;
  } else {
    float v = bias[NCOL + j];
#pragma unroll
    for (int c = 0; c < NCE; ++c) v += p_emg[c * n + o];
    out[n + o] = v;
  }
}

extern "C" void kernel_launch(void* const* d_in, const int* in_sizes, int n_in,
                              void* d_out, int out_size, void* d_ws, size_t ws_size,
                              hipStream_t stream) {
  const float* x_imu     = (const float*)d_in[0];
  const float* x_emg     = (const float*)d_in[1];
  const int*   lens      = (const int*)d_in[2];
  const float* w_emb_imu = (const float*)d_in[3];
  const float* b_emb_imu = (const float*)d_in[4];
  const float* w_emb_emg = (const float*)d_in[5];
  const float* b_emb_emg = (const float*)d_in[6];
  const float* w_proj    = (const float*)d_in[7];
  const float* b_proj    = (const float*)d_in[8];
  float* out = (float*)d_out;

  const int B = in_sizes[2];
  const int T = in_sizes[0] / (B * CIMU);

  // workspace carve (all 16B aligned)
  char* ws = (char*)d_ws;
  __bf16* wcT_imu = (__bf16*)ws;                 ws += (size_t)NCOL * KIMU * 2;   // 3.69 MB
  __bf16* wcT_emg = (__bf16*)ws;                 ws += (size_t)NCOL * KEMG * 2;   // 1.23 MB
  float*  bias    = (float*)ws;                  ws += 2 * NCOL * 4;
  float*  bpart   = (float*)ws;                  ws += (size_t)2 * NEWL * NCOL * 4;
  __bf16* xi_imu  = (__bf16*)ws;                 ws += (size_t)B * KIMU * 2;      // 29.5 MB
  __bf16* xi_emg  = (__bf16*)ws;                 ws += (size_t)B * KEMG * 2;      // 9.8 MB
  float*  p_imu   = (float*)ws;                  ws += (size_t)NCI * B * NCOL * 4; // 18.9 MB
  float*  p_emg   = (float*)ws;                  ws += (size_t)NCE * B * NCOL * 4; // 6.3 MB

  wcomb_kernel<<<dim3(NEWL, 2), 256, 0, stream>>>(w_emb_imu, w_emb_emg, w_proj,
                                                  wcT_imu, wcT_emg);
  bias_partial_kernel<<<dim3(NEWL, 2), 256, 0, stream>>>(b_emb_imu, b_emb_emg,
                                                         w_proj, bpart);
  bias_reduce_kernel<<<2, 256, 0, stream>>>(b_proj, bpart, bias);
  interp_kernel<<<(B * NEWL + 3) / 4, 256, 0, stream>>>(x_imu, x_emg, lens,
                                                        xi_imu, xi_emg, B, T);
  const int upk = (B / 64) * 4;  // 128
  mfma_gemm_kernel<<<(NCI + NCE) * upk, 256, 0, stream>>>(
      xi_imu, xi_emg, wcT_imu, wcT_emg, p_imu, p_emg, B);
  combine_kernel<<<dim3(B, 2), 256, 0, stream>>>(bias, p_imu, p_emg, out, B);
}

// Round 3
// 107.258 us; speedup vs baseline: 4.6713x; 1.6577x over previous
//
#include <hip/hip_runtime.h>

#define NEWL 150
#define EMBD 64
#define NCOL 256
#define CIMU 48
#define CEMG 16

#define KIMU (NEWL * CIMU)  // 7200
#define KEMG (NEWL * CEMG)  // 2400
#define KSTI (KIMU / 32)    // 225 k-steps imu
#define KSTE (KEMG / 32)    // 75  k-steps emg
#define KSC 25              // k-steps per split-K chunk (K=800)
#define NCI (KSTI / KSC)    // 9 imu chunks
#define NCE (KSTE / KSC)    // 3 emg chunks

typedef __bf16 bf16x8_t __attribute__((ext_vector_type(8)));
typedef __bf16 bf16x4_t __attribute__((ext_vector_type(4)));
typedef float f32x4_t __attribute__((ext_vector_type(4)));

__device__ __forceinline__ f32x4_t mfma16(bf16x8_t a, bf16x8_t b, f32x4_t c) {
  return __builtin_amdgcn_mfma_f32_16x16x32_bf16(a, b, c, 0, 0, 0);
}

__device__ __forceinline__ void gll16(const __bf16* g, __bf16* l) {
  __builtin_amdgcn_global_load_lds(
      (const __attribute__((address_space(1))) void*)g,
      (__attribute__((address_space(3))) void*)l, 16, 0, 0);
}

// ---------- K0: combined weights packed in MFMA B-fragment order + bias partials.
// W_pack[cb][ks][lane][8]: lane = h*16 + (col&15), cb = col>>4, k = ks*32+h*8+t
template <int C, int KST>
__device__ void wcomb_body(const float* __restrict__ wemb,
                           const float* __restrict__ wreg_src,
                           __bf16* __restrict__ wpk, int s, int j) {
  float wreg[EMBD];
#pragma unroll
  for (int e = 0; e < EMBD; ++e) wreg[e] = wreg_src[(size_t)e * NCOL];
  const int cb = j >> 4, lr = j & 15;
#pragma unroll
  for (int q = 0; q < C / 8; ++q) {
    const int kq = (s * C) / 8 + q;  // k/8
    const int ks = kq >> 2, h = kq & 3;
    bf16x8_t tv;
#pragma unroll
    for (int u = 0; u < 8; ++u) {
      const float* we = wemb + (q * 8 + u) * EMBD;
      float acc = 0.f;
#pragma unroll
      for (int e = 0; e < EMBD; ++e) acc = fmaf(we[e], wreg[e], acc);
      tv[u] = (__bf16)acc;
    }
    *(bf16x8_t*)(wpk + (((size_t)cb * KST + ks) * 64 + h * 16 + lr) * 8) = tv;
  }
}

__global__ __launch_bounds__(256) void wcomb_kernel(
    const float* __restrict__ w_emb_imu, const float* __restrict__ w_emb_emg,
    const float* __restrict__ b_emb_imu, const float* __restrict__ b_emb_emg,
    const float* __restrict__ w_proj,
    __bf16* __restrict__ wpk_imu, __bf16* __restrict__ wpk_emg,
    float* __restrict__ bpart) {
  const int s = blockIdx.x;   // 0..149
  const int m = blockIdx.y;   // 0 = imu, 1 = emg
  const int j = threadIdx.x;  // output column 0..255
  const float* wp_base = w_proj + (size_t)s * EMBD * NCOL + j;
  // bias partial reuses the same w_proj slice
  const float* be = (m == 0) ? b_emb_imu : b_emb_emg;
  float bacc = 0.f;
#pragma unroll
  for (int e = 0; e < EMBD; ++e) bacc = fmaf(be[e], wp_base[(size_t)e * NCOL], bacc);
  bpart[((size_t)m * NEWL + s) * NCOL + j] = bacc;
  if (m == 0)
    wcomb_body<CIMU, KSTI>(w_emb_imu, wp_base, wpk_imu, s, j);
  else
    wcomb_body<CEMG, KSTE>(w_emb_emg, wp_base, wpk_emg, s, j);
}

__global__ __launch_bounds__(256) void bias_reduce_kernel(
    const float* __restrict__ b_proj, const float* __restrict__ bpart,
    float* __restrict__ bias) {
  const int m = blockIdx.x, j = threadIdx.x;
  float acc = b_proj[j];
  for (int s = 0; s < NEWL; ++s) acc += bpart[((size_t)m * NEWL + s) * NCOL + j];
  bias[m * NCOL + j] = acc;
}

// ---------- K2: ragged interp, float4 loads, 2 samples per wave
__global__ __launch_bounds__(256) void interp_kernel(
    const float* __restrict__ x_imu, const float* __restrict__ x_emg,
    const int* __restrict__ lens,
    __bf16* __restrict__ xi_imu, __bf16* __restrict__ xi_emg, int B, int T) {
  const int tid = threadIdx.x;
  const int g32 = blockIdx.x * 8 + (tid >> 5);  // one 32-lane group per (b,s)
  const int lane = tid & 63;
  const int g = tid & 31;
  const int b = g32 / NEWL;
  const int s = g32 - b * NEWL;
  if (b >= B) return;
  const int len = lens[b];
  const float scale = (float)len / 150.0f;
  float src = ((float)s + 0.5f) * scale - 0.5f;
  src = fmaxf(src, 0.0f);
  int i0 = (int)floorf(src);
  i0 = min(i0, len - 1);
  const int i1 = min(i0 + 1, len - 1);
  const float w = src - (float)i0;

  float4 v;
  if (g < 24) {  // imu: g<12 -> row i0 chunk g ; g in 12..23 -> row i1 chunk g-12
    const int ci = (g < 12) ? g : g - 12;
    const int ir = (g < 12) ? i0 : i1;
    v = *(const float4*)(x_imu + ((size_t)b * T + ir) * CIMU + ci * 4);
  } else {       // emg: 24..27 -> i0 chunk g-24 ; 28..31 -> i1 chunk g-28
    const int ci = g & 3;
    const int ir = (g < 28) ? i0 : i1;
    v = *(const float4*)(x_emg + ((size_t)b * T + ir) * CEMG + ci * 4);
  }
  const int base = lane & 32;
  const int src_lane = (g < 24) ? (base + g + 12) : (base + g + 4);
  float4 pv;
  pv.x = __shfl(v.x, src_lane);
  pv.y = __shfl(v.y, src_lane);
  pv.z = __shfl(v.z, src_lane);
  pv.w = __shfl(v.w, src_lane);

  bf16x4_t o;
  o[0] = (__bf16)(v.x * (1.0f - w) + pv.x * w);
  o[1] = (__bf16)(v.y * (1.0f - w) + pv.y * w);
  o[2] = (__bf16)(v.z * (1.0f - w) + pv.z * w);
  o[3] = (__bf16)(v.w * (1.0f - w) + pv.w * w);
  if (g < 12) {
    *(bf16x4_t*)(xi_imu + ((size_t)b * NEWL + s) * CIMU + g * 4) = o;
  } else if (g >= 24 && g < 28) {
    *(bf16x4_t*)(xi_emg + ((size_t)b * NEWL + s) * CEMG + (g - 24) * 4) = o;
  }
}

// ---------- K3: MFMA GEMM: A LDS-staged (global_load_lds, double-buffered),
// B direct from packed-fragment global (coalesced). BM=64 BN=128, split-K 800.
__global__ __launch_bounds__(256) void mfma_gemm_kernel(
    const __bf16* __restrict__ xi_imu, const __bf16* __restrict__ xi_emg,
    const __bf16* __restrict__ wpk_imu, const __bf16* __restrict__ wpk_emg,
    float* __restrict__ p_imu, float* __restrict__ p_emg, int B) {
  __shared__ __bf16 Ald[2][64 * 32];
  const int mtiles = B >> 6;   // 32
  const int upc = mtiles * 2;  // 64 units per chunk
  const int unit = blockIdx.x;
  const int c = unit / upc;
  const int t = unit - c * upc;
  const int mb = t >> 1, nb = t & 1;
  const __bf16* A;
  const __bf16* Wp;
  float* P;
  int KST, kc;
  if (c < NCI) {
    kc = c; A = xi_imu; Wp = wpk_imu; KST = KSTI;
    P = p_imu + (size_t)kc * B * NCOL;
  } else {
    kc = c - NCI; A = xi_emg; Wp = wpk_emg; KST = KSTE;
    P = p_emg + (size_t)kc * B * NCOL;
  }
  const int Ktot = KST * 32;
  const int ks0 = kc * KSC;

  const int tid = threadIdx.x, w = tid >> 6, l = tid & 63;
  const int wr = w >> 1, wn = w & 1;
  const int row0 = mb * 64;

  // staging: wave w covers rows w*16+(l>>2), 64B per row per step
  const __bf16* ag =
      A + (size_t)(row0 + w * 16 + (l >> 2)) * Ktot + (size_t)ks0 * 32 + (l & 3) * 8;
  __bf16* lw[2] = {&Ald[0][w * 16 * 32], &Ald[1][w * 16 * 32]};

  const int lr = l & 15, lh = l >> 4;
  const int a_off0 = (wr * 32 + lr) * 32 + lh * 8;
  const int a_off1 = a_off0 + 16 * 32;

  const int cb0 = nb * 8 + wn * 4;
  const __bf16* bg = Wp + ((size_t)cb0 * KST + ks0) * 64 * 8 + (size_t)l * 8;
  const size_t bplane = (size_t)KST * 64 * 8;

  f32x4_t z = {0.f, 0.f, 0.f, 0.f};
  f32x4_t acc[2][4];
#pragma unroll
  for (int i = 0; i < 2; ++i)
#pragma unroll
    for (int jj = 0; jj < 4; ++jj) acc[i][jj] = z;

  gll16(ag, lw[0]);
  __syncthreads();

  for (int ks = 0; ks < KSC; ++ks) {
    const __bf16* bks = bg + (size_t)ks * 64 * 8;
    const bf16x8_t bv0 = *(const bf16x8_t*)(bks);
    const bf16x8_t bv1 = *(const bf16x8_t*)(bks + bplane);
    const bf16x8_t bv2 = *(const bf16x8_t*)(bks + 2 * bplane);
    const bf16x8_t bv3 = *(const bf16x8_t*)(bks + 3 * bplane);
    if (ks + 1 < KSC) gll16(ag + (size_t)(ks + 1) * 32, lw[(ks + 1) & 1]);
    const __bf16* abase = &Ald[ks & 1][0];
    const bf16x8_t av0 = *(const bf16x8_t*)(abase + a_off0);
    const bf16x8_t av1 = *(const bf16x8_t*)(abase + a_off1);
    acc[0][0] = mfma16(av0, bv0, acc[0][0]);
    acc[0][1] = mfma16(av0, bv1, acc[0][1]);
    acc[0][2] = mfma16(av0, bv2, acc[0][2]);
    acc[0][3] = mfma16(av0, bv3, acc[0][3]);
    acc[1][0] = mfma16(av1, bv0, acc[1][0]);
    acc[1][1] = mfma16(av1, bv1, acc[1][1]);
    acc[1][2] = mfma16(av1, bv2, acc[1][2]);
    acc[1][3] = mfma16(av1, bv3, acc[1][3]);
    if (ks + 1 < KSC) __syncthreads();
  }

  const int orow = row0 + wr * 32 + lh * 4;
  const int ocol = nb * 128 + wn * 64 + lr;
  float* Pb = P + (size_t)orow * NCOL + ocol;
#pragma unroll
  for (int rb = 0; rb < 2; ++rb)
#pragma unroll
    for (int sub = 0; sub < 4; ++sub)
#pragma unroll
      for (int jj = 0; jj < 4; ++jj)
        Pb[(size_t)(rb * 16 + jj) * NCOL + sub * 16] = acc[rb][sub][jj];
}

// ---------- K4: sum split-K partials + bias -> d_out
__global__ __launch_bounds__(256) void combine_kernel(
    const float* __restrict__ bias, const float* __restrict__ p_imu,
    const float* __restrict__ p_emg, float* __restrict__ out, int B) {
  const int b = blockIdx.x, m = blockIdx.y, j = threadIdx.x;
  const size_t n = (size_t)B * NCOL;
  const size_t o = (size_t)b * NCOL + j;
  if (m == 0) {
    float v = bias[j];
#pragma unroll
    for (int c = 0; c < NCI; ++c) v += p_imu[c * n + o];
    out[o] = v;
  } else {
    float v = bias[NCOL + j];
#pragma unroll
    for (int c = 0; c < NCE; ++c) v += p_emg[c * n + o];
    out[n + o] = v;
  }
}

extern "C" void kernel_launch(void* const* d_in, const int* in_sizes, int n_in,
                              void* d_out, int out_size, void* d_ws, size_t ws_size,
                              hipStream_t stream) {
  const float* x_imu     = (const float*)d_in[0];
  const float* x_emg     = (const float*)d_in[1];
  const int*   lens      = (const int*)d_in[2];
  const float* w_emb_imu = (const float*)d_in[3];
  const float* b_emb_imu = (const float*)d_in[4];
  const float* w_emb_emg = (const float*)d_in[5];
  const float* b_emb_emg = (const float*)d_in[6];
  const float* w_proj    = (const float*)d_in[7];
  const float* b_proj    = (const float*)d_in[8];
  float* out = (float*)d_out;

  const int B = in_sizes[2];
  const int T = in_sizes[0] / (B * CIMU);

  char* ws = (char*)d_ws;
  __bf16* wpk_imu = (__bf16*)ws;  ws += (size_t)NCOL * KIMU * 2;
  __bf16* wpk_emg = (__bf16*)ws;  ws += (size_t)NCOL * KEMG * 2;
  float*  bias    = (float*)ws;   ws += 2 * NCOL * 4;
  float*  bpart   = (float*)ws;   ws += (size_t)2 * NEWL * NCOL * 4;
  __bf16* xi_imu  = (__bf16*)ws;  ws += (size_t)B * KIMU * 2;
  __bf16* xi_emg  = (__bf16*)ws;  ws += (size_t)B * KEMG * 2;
  float*  p_imu   = (float*)ws;   ws += (size_t)NCI * B * NCOL * 4;
  float*  p_emg   = (float*)ws;   ws += (size_t)NCE * B * NCOL * 4;

  wcomb_kernel<<<dim3(NEWL, 2), 256, 0, stream>>>(
      w_emb_imu, w_emb_emg, b_emb_imu, b_emb_emg, w_proj, wpk_imu, wpk_emg, bpart);
  bias_reduce_kernel<<<2, 256, 0, stream>>>(b_proj, bpart, bias);
  interp_kernel<<<B * NEWL / 8, 256, 0, stream>>>(x_imu, x_emg, lens,
                                                  xi_imu, xi_emg, B, T);
  const int units = (NCI + NCE) * (B / 64) * 2;  // 768
  mfma_gemm_kernel<<<units, 256, 0, stream>>>(xi_imu, xi_emg, wpk_imu, wpk_emg,
                                              p_imu, p_emg, B);
  combine_kernel<<<dim3(B, 2), 256, 0, stream>>>(bias, p_imu, p_emg, out, B);
}